// Round 15
// baseline (1725.457 us; speedup 1.0000x reference)
//
#include <hip/hip_runtime.h>
#include <hip/hip_bf16.h>
#include <math.h>

#define DEPTH 6
#define DIM   768
#define HEADS 12
#define DH    64
#define NCTX  1024
#define BATCH 8
#define ROWS  (BATCH*NCTX)   /* 8192 */
#define DIM3  (3*DIM)        /* 2304 */
#define DIMF  (4*DIM)        /* 3072 */
#define LNEPS 1e-5f

typedef __attribute__((ext_vector_type(8)))  short short8;
typedef __attribute__((ext_vector_type(4)))  float floatx4;
typedef __attribute__((ext_vector_type(16))) float floatx16;
using bf16 = __hip_bfloat16;
typedef unsigned int u32;

static __device__ __forceinline__ bf16 f2bf(float v){ return __float2bfloat16(v); }
static __device__ __forceinline__ float bf2f(unsigned short u){
    union { unsigned int i; float f; } c; c.i = ((unsigned int)u) << 16; return c.f;
}
static __device__ __forceinline__ unsigned short bfu(float v){ return __bfloat16_as_ushort(f2bf(v)); }
static __device__ __forceinline__ u32 pk2(float a, float b){
    return (u32)bfu(a) | ((u32)bfu(b) << 16);
}

// async global->LDS, 16B per lane (dest must be wave-uniform base + lane*16)
static __device__ __forceinline__ void gl_lds16(const void* g, void* l) {
    __builtin_amdgcn_global_load_lds((const __attribute__((address_space(1))) void*)g,
                                     (__attribute__((address_space(3))) void*)l, 16, 0, 0);
}

// ---------------------------------------------------------------------------
// W [L][K][N] fp32  ->  WT [L][N][K] bf16   (tiled transpose via LDS)
// ---------------------------------------------------------------------------
__global__ void k_transpose_convert(const float* __restrict__ W, bf16* __restrict__ WT,
                                    int K, int N) {
    __shared__ float tile[32][33];
    int l = blockIdx.z;
    const float* Wl = W + (size_t)l * K * N;
    bf16* WTl = WT + (size_t)l * K * N;
    int n0 = blockIdx.x * 32, k0 = blockIdx.y * 32;
    int tx = threadIdx.x, ty = threadIdx.y;
#pragma unroll
    for (int i = 0; i < 4; i++)
        tile[ty + i*8][tx] = Wl[(size_t)(k0 + ty + i*8) * N + n0 + tx];
    __syncthreads();
#pragma unroll
    for (int i = 0; i < 4; i++)
        WTl[(size_t)(n0 + ty + i*8) * K + k0 + tx] = f2bf(tile[tx][ty + i*8]);
}

// ---------------------------------------------------------------------------
// LayerNorm: x fp32 [ROWS][DIM] -> y bf16.  One wave per row, float4 loads.
// ---------------------------------------------------------------------------
__global__ __launch_bounds__(256) void k_layernorm(const float* __restrict__ x,
                                                   const float* __restrict__ g,
                                                   const float* __restrict__ b,
                                                   bf16* __restrict__ y) {
    int row  = blockIdx.x * 4 + (threadIdx.x >> 6);
    int lane = threadIdx.x & 63;
    const float4* xr = (const float4*)(x + (size_t)row * DIM);
    float4 v[3];
    float s = 0.f, s2 = 0.f;
#pragma unroll
    for (int i = 0; i < 3; i++) {
        v[i] = xr[lane + i*64];
        s  += v[i].x + v[i].y + v[i].z + v[i].w;
        s2 += v[i].x*v[i].x + v[i].y*v[i].y + v[i].z*v[i].z + v[i].w*v[i].w;
    }
#pragma unroll
    for (int m = 1; m < 64; m <<= 1) { s += __shfl_xor(s, m); s2 += __shfl_xor(s2, m); }
    float mu  = s * (1.f / DIM);
    float var = s2 * (1.f / DIM) - mu * mu;
    float rs  = rsqrtf(var + LNEPS);
    bf16* yr = y + (size_t)row * DIM;
    const float4* g4 = (const float4*)g;
    const float4* b4 = (const float4*)b;
#pragma unroll
    for (int i = 0; i < 3; i++) {
        float4 gg = g4[lane + i*64], bb = b4[lane + i*64];
        float r0 = (v[i].x - mu) * rs * gg.x + bb.x;
        float r1 = (v[i].y - mu) * rs * gg.y + bb.y;
        float r2 = (v[i].z - mu) * rs * gg.z + bb.z;
        float r3 = (v[i].w - mu) * rs * gg.w + bb.w;
        uint2 u; u.x = pk2(r0, r1); u.y = pk2(r2, r3);
        *(uint2*)&yr[4 * (lane + i*64)] = u;
    }
}

// ---------------------------------------------------------------------------
// 3-buffer counted-vmcnt GEMM, BM/BN/BK templated, T2 chunk-XOR swizzle
// (pre-swizzled global source + XOR'd fragment read; linear LDS dest).
// BK=32 path identical to R13/R14 (conflicts==0 proven).  BK=64 (MLP2):
// halves K-step count -> 16 MFMA + 12 ds_read per barrier instead of 8+6.
// MODE 0 writes the V third (cols >= 1536) transposed to vT[b][h][d][n].
// ---------------------------------------------------------------------------
template<int MODE, int BM, int BN, int BK>
__global__ __launch_bounds__(256, 2) void k_gemm(const bf16* __restrict__ A,
                                                 const bf16* __restrict__ WT,
                                                 const float* __restrict__ bias,
                                                 bf16* __restrict__ outb,
                                                 float* __restrict__ outf,
                                                 bf16* __restrict__ vT,
                                                 int N, int K) {
    constexpr int IF  = BM / 32;
    constexpr int JF  = BN / 32;
    constexpr int KK  = BK / 32;                    // MFMA k-subtiles per step
    constexpr int ACH = BM * BK / 2048;             // A chunks per thread
    constexpr int BCH = BN * BK / 2048;             // B chunks per thread
    constexpr int LPT = ACH + BCH;
    __shared__ __align__(16) bf16 As[3][BM*BK];
    __shared__ __align__(16) bf16 Bs[3][BN*BK];
    int nt = N / BN;
    int nwg = gridDim.x;
    int fblk = blockIdx.x;
    int swz = (fblk & 7) * (nwg >> 3) + (fblk >> 3);
    int m0 = (swz / nt) * BM, n0 = (swz % nt) * BN;
    int t = threadIdx.x;
    int lane = t & 63, w = t >> 6;
    int wr = (w >> 1) * (BM / 2), wc = (w & 1) * (BN / 2);
    int lr = lane & 15, lg = lane >> 4;
    int fcol = (lg ^ ((lane >> 1) & 3)) * 8;        // BK=32 read chunk XOR

    floatx4 acc[IF][JF] = {};
    int NT = K / BK;                                // 24 (BK32) or 48 (BK64); %3==0

    auto SRCCOL = [&](int c) {                      // source pre-swizzle
        if constexpr (BK == 32) return ((c & 3) ^ ((c >> 3) & 3)) * 8;
        else                    return ((c & 7) ^ ((c >> 3) & 7)) * 8;
    };
    auto STAGE = [&](int ks, int buf) {
        int ko = ks * BK;
#pragma unroll
        for (int ac = 0; ac < ACH; ac++) {
            int c = ac*256 + t;
            int row = c / (BK/8);
            gl_lds16(A + (size_t)(m0 + row) * K + ko + SRCCOL(c), &As[buf][c * 8]);
        }
#pragma unroll
        for (int bc = 0; bc < BCH; bc++) {
            int c = bc*256 + t;
            int row = c / (BK/8);
            gl_lds16(WT + (size_t)(n0 + row) * K + ko + SRCCOL(c), &Bs[buf][c * 8]);
        }
    };
    auto WAITC = [&]() {
        if constexpr (LPT == 6)      asm volatile("s_waitcnt vmcnt(6)" ::: "memory");
        else if constexpr (LPT == 4) asm volatile("s_waitcnt vmcnt(4)" ::: "memory");
        else                         asm volatile("s_waitcnt vmcnt(3)" ::: "memory");
    };

    STAGE(0, 0);
    STAGE(1, 1);
    WAITC();
    __builtin_amdgcn_s_barrier();

    for (int kb = 0; kb < NT; kb += 3) {
#pragma unroll
        for (int s = 0; s < 3; s++) {
            int ks = kb + s;
            bool pf = (ks + 2) < NT;
            if (pf) STAGE(ks + 2, (s + 2) % 3);
            short8 af[IF][KK], bfr[JF][KK];
#pragma unroll
            for (int kk = 0; kk < KK; kk++) {
#pragma unroll
                for (int i = 0; i < IF; i++) {
                    int row = wr + i*16 + lr;
                    int ch = (BK == 32) ? fcol : ((4*kk + lg) ^ (lr & 7)) * 8;
                    af[i][kk] = *(const short8*)&As[s][row*BK + ch];
                }
#pragma unroll
                for (int j = 0; j < JF; j++) {
                    int row = wc + j*16 + lr;
                    int ch = (BK == 32) ? fcol : ((4*kk + lg) ^ (lr & 7)) * 8;
                    bfr[j][kk] = *(const short8*)&Bs[s][row*BK + ch];
                }
            }
            __builtin_amdgcn_s_setprio(1);
#pragma unroll
            for (int kk = 0; kk < KK; kk++)
#pragma unroll
                for (int i = 0; i < IF; i++)
#pragma unroll
                    for (int j = 0; j < JF; j++)
                        acc[i][j] = __builtin_amdgcn_mfma_f32_16x16x32_bf16(af[i][kk], bfr[j][kk], acc[i][j], 0, 0, 0);
            __builtin_amdgcn_s_setprio(0);
            if (pf) WAITC();
            else    asm volatile("s_waitcnt vmcnt(0)" ::: "memory");
            __builtin_amdgcn_s_barrier();
        }
    }
#pragma unroll
    for (int i = 0; i < IF; i++)
#pragma unroll
        for (int j = 0; j < JF; j++) {
            int row0 = m0 + wr + i*16 + lg*4;
            int col  = n0 + wc + j*16 + lr;
            float bz = bias[col];
            float vv[4];
#pragma unroll
            for (int r = 0; r < 4; r++) vv[r] = acc[i][j][r] + bz;
            if (MODE == 0 && n0 >= 2*DIM) {          // V third -> transposed vT
                int h = (col - 2*DIM) >> 6, d = (col - 2*DIM) & 63;
                int bb = row0 >> 10, n = row0 & 1023;
                uint2 u; u.x = pk2(vv[0], vv[1]); u.y = pk2(vv[2], vv[3]);
                *(uint2*)(vT + (((size_t)bb*12 + h)*64 + d)*1024 + n) = u;
            } else {
#pragma unroll
                for (int r = 0; r < 4; r++) {
                    if (MODE == 0) {
                        outb[(size_t)(row0+r) * N + col] = f2bf(vv[r]);
                    } else if (MODE == 1) {
                        float vx = vv[r];
                        float u = 1.5957691216f * (vx + 0.044715f * vx * vx * vx);
                        float gs = 1.f / (1.f + __expf(-u));
                        outb[(size_t)(row0+r) * N + col] = f2bf(vx * gs);
                    } else {
                        outf[(size_t)(row0+r) * N + col] += vv[r];
                    }
                }
            }
        }
}

// ---------------------------------------------------------------------------
// Flash attention (R14): all-DMA K/V staging via gl_lds16 (pre-swizzled global
// source, linear LDS dest), double-buffered, one vmcnt(0)+barrier per tile.
// V from vT[b][h][d][n].  Swapped 32x32 QK^T, in-lane exp2 softmax, defer-max,
// T12 permlane P->A-frag, T5 setprio, fused residual add.
// ---------------------------------------------------------------------------
__global__ __launch_bounds__(256, 3) void k_attn(const bf16* __restrict__ qkv,
                                                 const bf16* __restrict__ vT,
                                                 float* __restrict__ x) {
    int f = blockIdx.x;           // 768 blocks; XCD = f % 8
    int b  = f & 7;
    int rr = f >> 3;
    int h  = rr % 12;
    int qt = rr / 12;
    int t = threadIdx.x, lane = t & 63, w = t >> 6;
    int q = lane & 31, hi = lane >> 5;
    const size_t bn0 = (size_t)b * NCTX;
    const bf16* Qg = qkv + bn0 * DIM3 + h * DH;
    const bf16* Kg = Qg + DIM;
    const bf16* Vt = vT + (((size_t)b*12 + h) * 64) * 1024;   // [d][n]
    int q0 = qt * 128 + w * 32;

    __shared__ __align__(16) bf16 Kb[2][64*64];
    __shared__ __align__(16) bf16 Vb[2][64*64];
    __shared__ float wbc[4][32];

    auto STAGE_KV = [&](int kt2, int buf) {
        int kv0 = kt2 * 64;
#pragma unroll
        for (int it = 0; it < 2; it++) {
            int i = it*256 + t;
            int r8 = i >> 3;                       // K row (k) / V row (d)
            int ulog = (i & 7) ^ (r8 & 7);         // source pre-swizzle
            gl_lds16(Kg + (size_t)(kv0 + r8) * DIM3 + ulog*8, &Kb[buf][i*8]);
            gl_lds16(Vt + (size_t)r8 * 1024 + kv0 + ulog*8,   &Vb[buf][i*8]);
        }
    };

    STAGE_KV(0, 0);               // DMA flies under Q prep

    const float qs = 0.036084391824351615f * 1.4426950408889634f;  // 768^-0.5 * log2e
    short8 qf[4];
#pragma unroll
    for (int s = 0; s < 4; s++) {
        short8 raw = *(const short8*)&Qg[(size_t)(q0 + q) * DIM3 + s*16 + hi*8];
        short8 o;
#pragma unroll
        for (int e = 0; e < 8; e++)
            o[e] = (short)bfu(bf2f((unsigned short)raw[e]) * qs);
        qf[s] = o;
    }

    floatx16 pacc[2] = {};
    float mrow = -3e38f, lrow = 0.f;

    asm volatile("s_waitcnt vmcnt(0)" ::: "memory");
    __builtin_amdgcn_s_barrier();

    for (int kt = 0; kt < 16; kt++) {
        int cur = kt & 1;
        if (kt + 1 < 16) STAGE_KV(kt + 1, cur ^ 1);   // flies under this tile

        u32* ksw = (u32*)&Kb[cur][0];
        u32* vsw = (u32*)&Vb[cur][0];

        // ---- swapped QK^T
        floatx16 sacc[2] = {};
        __builtin_amdgcn_s_setprio(1);
#pragma unroll
        for (int kb = 0; kb < 2; kb++) {
#pragma unroll
            for (int s = 0; s < 4; s++) {
                int row = kb*32 + q;
                short8 kf = *(const short8*)(ksw + row*32 + (((2*s + hi) ^ (row & 7)) << 2));
                sacc[kb] = __builtin_amdgcn_mfma_f32_32x32x16_bf16(kf, qf[s], sacc[kb], 0, 0, 0);
            }
        }
        __builtin_amdgcn_s_setprio(0);

        // ---- in-lane softmax (exp2 domain, defer-max THR=8)
        float mx = sacc[0][0];
#pragma unroll
        for (int r = 1; r < 16; r++) mx = fmaxf(mx, sacc[0][r]);
#pragma unroll
        for (int r = 0; r < 16; r++) mx = fmaxf(mx, sacc[1][r]);
        mx = fmaxf(mx, __shfl_xor(mx, 32));
        bool chg = mx > mrow + 8.f;
        if (__any(chg)) {
            float mnew = chg ? mx : mrow;
            float corr = exp2f(mrow - mnew);
            mrow = mnew;
            lrow *= corr;
            wbc[w][q] = corr;
#pragma unroll
            for (int r = 0; r < 16; r++) {
                float c = wbc[w][(r & 3) + 8*(r >> 2) + 4*hi];
                pacc[0][r] *= c; pacc[1][r] *= c;
            }
        }

        // ---- P in-register -> A-frag via permlane32_swap (T12), fused PV
        float sum = 0.f;
#pragma unroll
        for (int kb = 0; kb < 2; kb++) {
            float pf[16];
#pragma unroll
            for (int r = 0; r < 16; r++) { pf[r] = exp2f(sacc[kb][r] - mrow); sum += pf[r]; }
#pragma unroll
            for (int g = 0; g < 2; g++) {
                u32 a0 = pk2(pf[8*g+0], pf[8*g+1]);
                u32 a1 = pk2(pf[8*g+2], pf[8*g+3]);
                u32 b0 = pk2(pf[8*g+4], pf[8*g+5]);
                u32 b1 = pk2(pf[8*g+6], pf[8*g+7]);
                asm volatile("v_permlane32_swap_b32 %0, %1" : "+v"(a0), "+v"(b0));
                asm volatile("v_permlane32_swap_b32 %0, %1" : "+v"(a1), "+v"(b1));
                union { u32 u[4]; short8 s8; } pa;
                pa.u[0] = a0; pa.u[1] = a1; pa.u[2] = b0; pa.u[3] = b1;
                int ks = 2*kb + g;
                __builtin_amdgcn_s_setprio(1);
#pragma unroll
                for (int db = 0; db < 2; db++) {
                    int dd = db*32 + q;
                    short8 vb = *(const short8*)(vsw + dd*32 + (((2*ks + hi) ^ (dd & 7)) << 2));
                    pacc[db] = __builtin_amdgcn_mfma_f32_32x32x16_bf16(pa.s8, vb, pacc[db], 0, 0, 0);
                }
                __builtin_amdgcn_s_setprio(0);
            }
        }
        sum += __shfl_xor(sum, 32);
        lrow += sum;

        asm volatile("s_waitcnt vmcnt(0)" ::: "memory");  // next tile landed
        __builtin_amdgcn_s_barrier();
    }

    // ---- epilogue
    wbc[w][q] = 1.f / lrow;
    float* xr = x + bn0 * DIM + (size_t)h * DH;
#pragma unroll
    for (int r = 0; r < 16; r++) {
        int qrow = (r & 3) + 8*(r >> 2) + 4*hi;
        float li = wbc[w][qrow];
#pragma unroll
        for (int db = 0; db < 2; db++) {
            int col = db*32 + q;
            xr[(size_t)(q0 + qrow) * DIM + col] += pacc[db][r] * li;
        }
    }
}

// ---------------------------------------------------------------------------
extern "C" void kernel_launch(void* const* d_in, const int* in_sizes, int n_in,
                              void* d_out, int out_size, void* d_ws, size_t ws_size,
                              hipStream_t stream) {
    const float* x_in  = (const float*)d_in[0];
    const float* ln1_g = (const float*)d_in[1];
    const float* ln1_b = (const float*)d_in[2];
    const float* wqkv  = (const float*)d_in[3];
    const float* bqkv  = (const float*)d_in[4];
    const float* ln2_g = (const float*)d_in[5];
    const float* ln2_b = (const float*)d_in[6];
    const float* w1    = (const float*)d_in[7];
    const float* b1    = (const float*)d_in[8];
    const float* w2    = (const float*)d_in[9];
    const float* b2    = (const float*)d_in[10];
    float* x = (float*)d_out;

    char* ws = (char*)d_ws;
    size_t off = 0;
    auto alloc = [&](size_t bytes) { void* p = ws + off; off += (bytes + 255) & ~255ull; return p; };
    bf16* wqkvT = (bf16*)alloc((size_t)DEPTH * DIM * DIM3 * 2);
    bf16* w1T   = (bf16*)alloc((size_t)DEPTH * DIM * DIMF * 2);
    bf16* w2T   = (bf16*)alloc((size_t)DEPTH * DIMF * DIM * 2);
    bf16* xn    = (bf16*)alloc((size_t)ROWS * DIM * 2);
    bf16* qkvh  = (bf16*)alloc((size_t)ROWS * DIMF * 2);
    bf16* vTb   = (bf16*)alloc((size_t)BATCH * HEADS * DH * NCTX * 2);
    if (off > ws_size) return;

    hipMemcpyAsync(x, x_in, (size_t)ROWS * DIM * 4, hipMemcpyDeviceToDevice, stream);

    k_transpose_convert<<<dim3(DIM3/32, DIM/32,  DEPTH), dim3(32, 8), 0, stream>>>(wqkv, wqkvT, DIM,  DIM3);
    k_transpose_convert<<<dim3(DIMF/32, DIM/32,  DEPTH), dim3(32, 8), 0, stream>>>(w1,   w1T,   DIM,  DIMF);
    k_transpose_convert<<<dim3(DIM/32,  DIMF/32, DEPTH), dim3(32, 8), 0, stream>>>(w2,   w2T,   DIMF, DIM);

    for (int l = 0; l < DEPTH; l++) {
        k_layernorm<<<ROWS/4, 256, 0, stream>>>(x, ln1_g + l*DIM, ln1_b + l*DIM, xn);
        k_gemm<0,256,128,32><<<dim3((DIM3/128)*(ROWS/256)), 256, 0, stream>>>(
            xn, wqkvT + (size_t)l*DIM*DIM3, bqkv + (size_t)l*DIM3, qkvh, nullptr, vTb, DIM3, DIM);
        k_attn<<<dim3(768), 256, 0, stream>>>(qkvh, vTb, x);
        k_layernorm<<<ROWS/4, 256, 0, stream>>>(x, ln2_g + l*DIM, ln2_b + l*DIM, xn);
        k_gemm<1,256,128,32><<<dim3((DIMF/128)*(ROWS/256)), 256, 0, stream>>>(
            xn, w1T + (size_t)l*DIM*DIMF, b1 + (size_t)l*DIMF, qkvh, nullptr, nullptr, DIMF, DIM);
        k_gemm<2,128,64,64><<<dim3((DIM/64)*(ROWS/128)), 256, 0, stream>>>(
            qkvh, w2T + (size_t)l*DIMF*DIM, b2 + (size_t)l*DIM, nullptr, x, nullptr, DIM, DIMF);
    }
}

// Round 16
// 1600.532 us; speedup vs baseline: 1.0781x; 1.0781x over previous
//
#include <hip/hip_runtime.h>
#include <hip/hip_bf16.h>
#include <math.h>

#define DEPTH 6
#define DIM   768
#define HEADS 12
#define DH    64
#define NCTX  1024
#define BATCH 8
#define ROWS  (BATCH*NCTX)   /* 8192 */
#define DIM3  (3*DIM)        /* 2304 */
#define DIMF  (4*DIM)        /* 3072 */
#define LNEPS 1e-5f

typedef __attribute__((ext_vector_type(8)))  short short8;
typedef __attribute__((ext_vector_type(4)))  float floatx4;
typedef __attribute__((ext_vector_type(16))) float floatx16;
using bf16 = __hip_bfloat16;
typedef unsigned int u32;

static __device__ __forceinline__ bf16 f2bf(float v){ return __float2bfloat16(v); }
static __device__ __forceinline__ float bf2f(unsigned short u){
    union { unsigned int i; float f; } c; c.i = ((unsigned int)u) << 16; return c.f;
}
static __device__ __forceinline__ unsigned short bfu(float v){ return __bfloat16_as_ushort(f2bf(v)); }
static __device__ __forceinline__ u32 pk2(float a, float b){
    return (u32)bfu(a) | ((u32)bfu(b) << 16);
}

// async global->LDS, 16B per lane (dest must be wave-uniform base + lane*16)
static __device__ __forceinline__ void gl_lds16(const void* g, void* l) {
    __builtin_amdgcn_global_load_lds((const __attribute__((address_space(1))) void*)g,
                                     (__attribute__((address_space(3))) void*)l, 16, 0, 0);
}

// ---------------------------------------------------------------------------
// W [L][K][N] fp32  ->  WT [L][N][K] bf16   (tiled transpose via LDS)
// ---------------------------------------------------------------------------
__global__ void k_transpose_convert(const float* __restrict__ W, bf16* __restrict__ WT,
                                    int K, int N) {
    __shared__ float tile[32][33];
    int l = blockIdx.z;
    const float* Wl = W + (size_t)l * K * N;
    bf16* WTl = WT + (size_t)l * K * N;
    int n0 = blockIdx.x * 32, k0 = blockIdx.y * 32;
    int tx = threadIdx.x, ty = threadIdx.y;
#pragma unroll
    for (int i = 0; i < 4; i++)
        tile[ty + i*8][tx] = Wl[(size_t)(k0 + ty + i*8) * N + n0 + tx];
    __syncthreads();
#pragma unroll
    for (int i = 0; i < 4; i++)
        WTl[(size_t)(n0 + ty + i*8) * K + k0 + tx] = f2bf(tile[tx][ty + i*8]);
}

// ---------------------------------------------------------------------------
// LayerNorm: x fp32 [ROWS][DIM] -> y bf16.  One wave per row, float4 loads.
// ---------------------------------------------------------------------------
__global__ __launch_bounds__(256) void k_layernorm(const float* __restrict__ x,
                                                   const float* __restrict__ g,
                                                   const float* __restrict__ b,
                                                   bf16* __restrict__ y) {
    int row  = blockIdx.x * 4 + (threadIdx.x >> 6);
    int lane = threadIdx.x & 63;
    const float4* xr = (const float4*)(x + (size_t)row * DIM);
    float4 v[3];
    float s = 0.f, s2 = 0.f;
#pragma unroll
    for (int i = 0; i < 3; i++) {
        v[i] = xr[lane + i*64];
        s  += v[i].x + v[i].y + v[i].z + v[i].w;
        s2 += v[i].x*v[i].x + v[i].y*v[i].y + v[i].z*v[i].z + v[i].w*v[i].w;
    }
#pragma unroll
    for (int m = 1; m < 64; m <<= 1) { s += __shfl_xor(s, m); s2 += __shfl_xor(s2, m); }
    float mu  = s * (1.f / DIM);
    float var = s2 * (1.f / DIM) - mu * mu;
    float rs  = rsqrtf(var + LNEPS);
    bf16* yr = y + (size_t)row * DIM;
    const float4* g4 = (const float4*)g;
    const float4* b4 = (const float4*)b;
#pragma unroll
    for (int i = 0; i < 3; i++) {
        float4 gg = g4[lane + i*64], bb = b4[lane + i*64];
        float r0 = (v[i].x - mu) * rs * gg.x + bb.x;
        float r1 = (v[i].y - mu) * rs * gg.y + bb.y;
        float r2 = (v[i].z - mu) * rs * gg.z + bb.z;
        float r3 = (v[i].w - mu) * rs * gg.w + bb.w;
        uint2 u; u.x = pk2(r0, r1); u.y = pk2(r2, r3);
        *(uint2*)&yr[4 * (lane + i*64)] = u;
    }
}

// ---------------------------------------------------------------------------
// 3-buffer counted-vmcnt GEMM (R14-proven, BK=32 only), T2 chunk-XOR swizzle.
// MODE 0 writes the V third (cols >= 1536) transposed to vT[b][h][d][n].
// ---------------------------------------------------------------------------
template<int MODE, int BM, int BN>
__global__ __launch_bounds__(256, 2) void k_gemm(const bf16* __restrict__ A,
                                                 const bf16* __restrict__ WT,
                                                 const float* __restrict__ bias,
                                                 bf16* __restrict__ outb,
                                                 float* __restrict__ outf,
                                                 bf16* __restrict__ vT,
                                                 int N, int K) {
    constexpr int IF  = BM / 32;
    constexpr int JF  = BN / 32;
    constexpr int LPT = BM / 64 + BN / 64;
    __shared__ __align__(16) bf16 As[3][BM*32];
    __shared__ __align__(16) bf16 Bs[3][BN*32];
    int nt = N / BN;
    int nwg = gridDim.x;
    int fblk = blockIdx.x;
    int swz = (fblk & 7) * (nwg >> 3) + (fblk >> 3);
    int m0 = (swz / nt) * BM, n0 = (swz % nt) * BN;
    int t = threadIdx.x;
    int lane = t & 63, w = t >> 6;
    int wr = (w >> 1) * (BM / 2), wc = (w & 1) * (BN / 2);
    int lr = lane & 15, lg = lane >> 4;
    int fcol = (lg ^ ((lane >> 1) & 3)) * 8;   // read-side chunk XOR

    floatx4 acc[IF][JF] = {};
    int NT = K >> 5;

    auto STAGE = [&](int ks, int buf) {
        int ko = ks << 5;
#pragma unroll
        for (int ac = 0; ac < BM/64; ac++) {
            int c = ac*256 + t;
            int row = c >> 2, col = ((c & 3) ^ ((c >> 3) & 3)) * 8;  // src pre-swizzle
            gl_lds16(A + (size_t)(m0 + row) * K + ko + col, &As[buf][c * 8]);
        }
#pragma unroll
        for (int bc = 0; bc < BN/64; bc++) {
            int c = bc*256 + t;
            int row = c >> 2, col = ((c & 3) ^ ((c >> 3) & 3)) * 8;
            gl_lds16(WT + (size_t)(n0 + row) * K + ko + col, &Bs[buf][c * 8]);
        }
    };
    auto WAITC = [&]() {
        if constexpr (LPT == 6)      asm volatile("s_waitcnt vmcnt(6)" ::: "memory");
        else if constexpr (LPT == 4) asm volatile("s_waitcnt vmcnt(4)" ::: "memory");
        else                         asm volatile("s_waitcnt vmcnt(3)" ::: "memory");
    };

    STAGE(0, 0);
    STAGE(1, 1);
    WAITC();
    __builtin_amdgcn_s_barrier();

    for (int kb = 0; kb < NT; kb += 3) {
#pragma unroll
        for (int s = 0; s < 3; s++) {
            int ks = kb + s;
            bool pf = (ks + 2) < NT;
            if (pf) STAGE(ks + 2, (s + 2) % 3);
            short8 af[IF], bfr[JF];
#pragma unroll
            for (int i = 0; i < IF; i++) af[i]  = *(const short8*)&As[s][(wr + i*16 + lr)*32 + fcol];
#pragma unroll
            for (int j = 0; j < JF; j++) bfr[j] = *(const short8*)&Bs[s][(wc + j*16 + lr)*32 + fcol];
            __builtin_amdgcn_s_setprio(1);
#pragma unroll
            for (int i = 0; i < IF; i++)
#pragma unroll
                for (int j = 0; j < JF; j++)
                    acc[i][j] = __builtin_amdgcn_mfma_f32_16x16x32_bf16(af[i], bfr[j], acc[i][j], 0, 0, 0);
            __builtin_amdgcn_s_setprio(0);
            if (pf) WAITC();
            else    asm volatile("s_waitcnt vmcnt(0)" ::: "memory");
            __builtin_amdgcn_s_barrier();
        }
    }
#pragma unroll
    for (int i = 0; i < IF; i++)
#pragma unroll
        for (int j = 0; j < JF; j++) {
            int row0 = m0 + wr + i*16 + lg*4;
            int col  = n0 + wc + j*16 + lr;
            float bz = bias[col];
            float vv[4];
#pragma unroll
            for (int r = 0; r < 4; r++) vv[r] = acc[i][j][r] + bz;
            if (MODE == 0 && n0 >= 2*DIM) {          // V third -> transposed vT
                int h = (col - 2*DIM) >> 6, d = (col - 2*DIM) & 63;
                int bb = row0 >> 10, n = row0 & 1023;
                uint2 u; u.x = pk2(vv[0], vv[1]); u.y = pk2(vv[2], vv[3]);
                *(uint2*)(vT + (((size_t)bb*12 + h)*64 + d)*1024 + n) = u;
            } else {
#pragma unroll
                for (int r = 0; r < 4; r++) {
                    if (MODE == 0) {
                        outb[(size_t)(row0+r) * N + col] = f2bf(vv[r]);
                    } else if (MODE == 1) {
                        float vx = vv[r];
                        float u = 1.5957691216f * (vx + 0.044715f * vx * vx * vx);
                        float gs = 1.f / (1.f + __expf(-u));
                        outb[(size_t)(row0+r) * N + col] = f2bf(vx * gs);
                    } else {
                        outf[(size_t)(row0+r) * N + col] += vv[r];
                    }
                }
            }
        }
}

// ---------------------------------------------------------------------------
// Flash attention: all-DMA K/V staging, now 3-buffer counted-vmcnt (T4):
// stage kt+2 at tile top; vmcnt(4) at tile end (kt+1 landed, kt+2 flying).
// V from vT[b][h][d][n].  Swapped 32x32 QK^T, in-lane exp2 softmax, defer-max,
// T12 permlane P->A-frag, T5 setprio, fused residual add.
// ---------------------------------------------------------------------------
__global__ __launch_bounds__(256, 3) void k_attn(const bf16* __restrict__ qkv,
                                                 const bf16* __restrict__ vT,
                                                 float* __restrict__ x) {
    int f = blockIdx.x;           // 768 blocks; XCD = f % 8
    int b  = f & 7;
    int rr = f >> 3;
    int h  = rr % 12;
    int qt = rr / 12;
    int t = threadIdx.x, lane = t & 63, w = t >> 6;
    int q = lane & 31, hi = lane >> 5;
    const size_t bn0 = (size_t)b * NCTX;
    const bf16* Qg = qkv + bn0 * DIM3 + h * DH;
    const bf16* Kg = Qg + DIM;
    const bf16* Vt = vT + (((size_t)b*12 + h) * 64) * 1024;   // [d][n]
    int q0 = qt * 128 + w * 32;

    __shared__ __align__(16) bf16 Kb[3][64*64];
    __shared__ __align__(16) bf16 Vb[3][64*64];
    __shared__ float wbc[4][32];

    auto STAGE_KV = [&](int kt2, int buf) {     // 4 loads/thread
        int kv0 = kt2 * 64;
#pragma unroll
        for (int it = 0; it < 2; it++) {
            int i = it*256 + t;
            int r8 = i >> 3;                       // K row (k) / V row (d)
            int ulog = (i & 7) ^ (r8 & 7);         // source pre-swizzle
            gl_lds16(Kg + (size_t)(kv0 + r8) * DIM3 + ulog*8, &Kb[buf][i*8]);
            gl_lds16(Vt + (size_t)r8 * 1024 + kv0 + ulog*8,   &Vb[buf][i*8]);
        }
    };

    STAGE_KV(0, 0);               // DMA flies under Q prep
    STAGE_KV(1, 1);

    const float qs = 0.036084391824351615f * 1.4426950408889634f;  // 768^-0.5 * log2e
    short8 qf[4];
#pragma unroll
    for (int s = 0; s < 4; s++) {
        short8 raw = *(const short8*)&Qg[(size_t)(q0 + q) * DIM3 + s*16 + hi*8];
        short8 o;
#pragma unroll
        for (int e = 0; e < 8; e++)
            o[e] = (short)bfu(bf2f((unsigned short)raw[e]) * qs);
        qf[s] = o;
    }

    floatx16 pacc[2] = {};
    float mrow = -3e38f, lrow = 0.f;

    asm volatile("s_waitcnt vmcnt(4)" ::: "memory");   // tile 0 landed, tile 1 flying
    __builtin_amdgcn_s_barrier();

    for (int kt = 0; kt < 16; kt++) {
        int cur = kt % 3;
        if (kt + 2 < 16) STAGE_KV(kt + 2, (kt + 2) % 3);   // 2 tiles of flight time

        u32* ksw = (u32*)&Kb[cur][0];
        u32* vsw = (u32*)&Vb[cur][0];

        // ---- swapped QK^T
        floatx16 sacc[2] = {};
        __builtin_amdgcn_s_setprio(1);
#pragma unroll
        for (int kb = 0; kb < 2; kb++) {
#pragma unroll
            for (int s = 0; s < 4; s++) {
                int row = kb*32 + q;
                short8 kf = *(const short8*)(ksw + row*32 + (((2*s + hi) ^ (row & 7)) << 2));
                sacc[kb] = __builtin_amdgcn_mfma_f32_32x32x16_bf16(kf, qf[s], sacc[kb], 0, 0, 0);
            }
        }
        __builtin_amdgcn_s_setprio(0);

        // ---- in-lane softmax (exp2 domain, defer-max THR=8)
        float mx = sacc[0][0];
#pragma unroll
        for (int r = 1; r < 16; r++) mx = fmaxf(mx, sacc[0][r]);
#pragma unroll
        for (int r = 0; r < 16; r++) mx = fmaxf(mx, sacc[1][r]);
        mx = fmaxf(mx, __shfl_xor(mx, 32));
        bool chg = mx > mrow + 8.f;
        if (__any(chg)) {
            float mnew = chg ? mx : mrow;
            float corr = exp2f(mrow - mnew);
            mrow = mnew;
            lrow *= corr;
            wbc[w][q] = corr;
#pragma unroll
            for (int r = 0; r < 16; r++) {
                float c = wbc[w][(r & 3) + 8*(r >> 2) + 4*hi];
                pacc[0][r] *= c; pacc[1][r] *= c;
            }
        }

        // ---- P in-register -> A-frag via permlane32_swap (T12), fused PV
        float sum = 0.f;
#pragma unroll
        for (int kb = 0; kb < 2; kb++) {
            float pf[16];
#pragma unroll
            for (int r = 0; r < 16; r++) { pf[r] = exp2f(sacc[kb][r] - mrow); sum += pf[r]; }
#pragma unroll
            for (int g = 0; g < 2; g++) {
                u32 a0 = pk2(pf[8*g+0], pf[8*g+1]);
                u32 a1 = pk2(pf[8*g+2], pf[8*g+3]);
                u32 b0 = pk2(pf[8*g+4], pf[8*g+5]);
                u32 b1 = pk2(pf[8*g+6], pf[8*g+7]);
                asm volatile("v_permlane32_swap_b32 %0, %1" : "+v"(a0), "+v"(b0));
                asm volatile("v_permlane32_swap_b32 %0, %1" : "+v"(a1), "+v"(b1));
                union { u32 u[4]; short8 s8; } pa;
                pa.u[0] = a0; pa.u[1] = a1; pa.u[2] = b0; pa.u[3] = b1;
                int ks = 2*kb + g;
                __builtin_amdgcn_s_setprio(1);
#pragma unroll
                for (int db = 0; db < 2; db++) {
                    int dd = db*32 + q;
                    short8 vb = *(const short8*)(vsw + dd*32 + (((2*ks + hi) ^ (dd & 7)) << 2));
                    pacc[db] = __builtin_amdgcn_mfma_f32_32x32x16_bf16(pa.s8, vb, pacc[db], 0, 0, 0);
                }
                __builtin_amdgcn_s_setprio(0);
            }
        }
        sum += __shfl_xor(sum, 32);
        lrow += sum;

        if (kt + 1 < 16) asm volatile("s_waitcnt vmcnt(4)" ::: "memory");  // kt+1 landed
        __builtin_amdgcn_s_barrier();
    }

    // ---- epilogue
    wbc[w][q] = 1.f / lrow;
    float* xr = x + bn0 * DIM + (size_t)h * DH;
#pragma unroll
    for (int r = 0; r < 16; r++) {
        int qrow = (r & 3) + 8*(r >> 2) + 4*hi;
        float li = wbc[w][qrow];
#pragma unroll
        for (int db = 0; db < 2; db++) {
            int col = db*32 + q;
            xr[(size_t)(q0 + qrow) * DIM + col] += pacc[db][r] * li;
        }
    }
}

// ---------------------------------------------------------------------------
extern "C" void kernel_launch(void* const* d_in, const int* in_sizes, int n_in,
                              void* d_out, int out_size, void* d_ws, size_t ws_size,
                              hipStream_t stream) {
    const float* x_in  = (const float*)d_in[0];
    const float* ln1_g = (const float*)d_in[1];
    const float* ln1_b = (const float*)d_in[2];
    const float* wqkv  = (const float*)d_in[3];
    const float* bqkv  = (const float*)d_in[4];
    const float* ln2_g = (const float*)d_in[5];
    const float* ln2_b = (const float*)d_in[6];
    const float* w1    = (const float*)d_in[7];
    const float* b1    = (const float*)d_in[8];
    const float* w2    = (const float*)d_in[9];
    const float* b2    = (const float*)d_in[10];
    float* x = (float*)d_out;

    char* ws = (char*)d_ws;
    size_t off = 0;
    auto alloc = [&](size_t bytes) { void* p = ws + off; off += (bytes + 255) & ~255ull; return p; };
    bf16* wqkvT = (bf16*)alloc((size_t)DEPTH * DIM * DIM3 * 2);
    bf16* w1T   = (bf16*)alloc((size_t)DEPTH * DIM * DIMF * 2);
    bf16* w2T   = (bf16*)alloc((size_t)DEPTH * DIMF * DIM * 2);
    bf16* xn    = (bf16*)alloc((size_t)ROWS * DIM * 2);
    bf16* qkvh  = (bf16*)alloc((size_t)ROWS * DIMF * 2);
    bf16* vTb   = (bf16*)alloc((size_t)BATCH * HEADS * DH * NCTX * 2);
    if (off > ws_size) return;

    hipMemcpyAsync(x, x_in, (size_t)ROWS * DIM * 4, hipMemcpyDeviceToDevice, stream);

    k_transpose_convert<<<dim3(DIM3/32, DIM/32,  DEPTH), dim3(32, 8), 0, stream>>>(wqkv, wqkvT, DIM,  DIM3);
    k_transpose_convert<<<dim3(DIMF/32, DIM/32,  DEPTH), dim3(32, 8), 0, stream>>>(w1,   w1T,   DIM,  DIMF);
    k_transpose_convert<<<dim3(DIM/32,  DIMF/32, DEPTH), dim3(32, 8), 0, stream>>>(w2,   w2T,   DIMF, DIM);

    for (int l = 0; l < DEPTH; l++) {
        k_layernorm<<<ROWS/4, 256, 0, stream>>>(x, ln1_g + l*DIM, ln1_b + l*DIM, xn);
        k_gemm<0,256,128><<<dim3((DIM3/128)*(ROWS/256)), 256, 0, stream>>>(
            xn, wqkvT + (size_t)l*DIM*DIM3, bqkv + (size_t)l*DIM3, qkvh, nullptr, vTb, DIM3, DIM);
        k_attn<<<dim3(768), 256, 0, stream>>>(qkvh, vTb, x);
        k_layernorm<<<ROWS/4, 256, 0, stream>>>(x, ln2_g + l*DIM, ln2_b + l*DIM, xn);
        k_gemm<1,256,128><<<dim3((DIMF/128)*(ROWS/256)), 256, 0, stream>>>(
            xn, w1T + (size_t)l*DIM*DIMF, b1 + (size_t)l*DIMF, qkvh, nullptr, nullptr, DIMF, DIM);
        k_gemm<2,128,64><<<dim3((DIM/64)*(ROWS/128)), 256, 0, stream>>>(
            qkvh, w2T + (size_t)l*DIMF*DIM, b2 + (size_t)l*DIM, nullptr, x, nullptr, DIM, DIMF);
    }
}